// Round 3
// baseline (958.444 us; speedup 1.0000x reference)
//
#include <hip/hip_runtime.h>

#define T_TOKENS 2048
#define DIM 1024
#define ISZ 2048
#define NEXP 8
#define NPAIRS (T_TOKENS * 2)
#define CAP (NPAIRS + 128)

typedef __attribute__((ext_vector_type(8))) short bf16x8;
typedef __attribute__((ext_vector_type(4))) float f32x4;

// ---------------- ws layout ----------------
constexpr size_t OFF_COUNTS = 0;
constexpr size_t OFF_CURSOR = 32;
constexpr size_t OFF_OFFSETS = 64;
constexpr size_t OFF_TOPK_I = 128;
constexpr size_t OFF_TOPK_W = OFF_TOPK_I + (size_t)NPAIRS * 4;
constexpr size_t OFF_ROW_T  = OFF_TOPK_W + (size_t)NPAIRS * 4;
constexpr size_t OFF_ROW_W  = OFF_ROW_T + (size_t)CAP * 4;
constexpr size_t OFF_XG     = (OFF_ROW_W + (size_t)CAP * 4 + 255) & ~(size_t)255;
constexpr size_t OFF_H      = OFF_XG + (size_t)CAP * DIM * 2;

__device__ __forceinline__ ushort f2bf(float f) {
    union { float f; unsigned u; } v; v.f = f;
    unsigned u = v.u;
    u += 0x7FFFu + ((u >> 16) & 1u);   // RNE
    return (ushort)(u >> 16);
}

__device__ __forceinline__ void cvt8_store(ushort* dst, float4 a, float4 b) {
    ushort4 c0; c0.x = f2bf(a.x); c0.y = f2bf(a.y); c0.z = f2bf(a.z); c0.w = f2bf(a.w);
    ushort4 c1; c1.x = f2bf(b.x); c1.y = f2bf(b.y); c1.z = f2bf(b.z); c1.w = f2bf(b.w);
    *(ushort4*)dst = c0;
    *(ushort4*)(dst + 4) = c1;
}

// ---------------- router: one wave per token ----------------
__global__ void router_kernel(const float* __restrict__ x,
                              const float* __restrict__ gw,
                              float* __restrict__ logits_out,
                              int* __restrict__ topk_idx,
                              float* __restrict__ topk_w,
                              int* __restrict__ counts) {
    int gwave = (int)((blockIdx.x * blockDim.x + threadIdx.x) >> 6);
    int lane = threadIdx.x & 63;
    if (gwave >= T_TOKENS) return;
    const float* xr = x + (size_t)gwave * DIM;
    float xv[16];
#pragma unroll
    for (int i = 0; i < 16; i++) xv[i] = xr[i * 64 + lane];
    float lg[8];
#pragma unroll
    for (int e = 0; e < 8; e++) {
        const float* g = gw + e * DIM;
        float s = 0.f;
#pragma unroll
        for (int i = 0; i < 16; i++) s += xv[i] * g[i * 64 + lane];
#pragma unroll
        for (int off = 32; off > 0; off >>= 1) s += __shfl_xor(s, off, 64);
        lg[e] = s;
    }
    if (lane == 0) {
#pragma unroll
        for (int e = 0; e < 8; e++) logits_out[gwave * 8 + e] = lg[e];
        int e0 = 0; float l0 = lg[0];
#pragma unroll
        for (int e = 1; e < 8; e++) if (lg[e] > l0) { l0 = lg[e]; e0 = e; }
        int e1 = -1; float l1 = -1e30f;
#pragma unroll
        for (int e = 0; e < 8; e++) if (e != e0 && lg[e] > l1) { l1 = lg[e]; e1 = e; }
        float w0 = 1.f / (1.f + __expf(l1 - l0));
        float w1 = 1.f - w0;
        topk_idx[gwave * 2] = e0; topk_idx[gwave * 2 + 1] = e1;
        topk_w[gwave * 2] = w0;  topk_w[gwave * 2 + 1] = w1;
        atomicAdd(&counts[e0], 1);
        atomicAdd(&counts[e1], 1);
    }
}

__global__ void scan_kernel(const int* __restrict__ counts, int* __restrict__ offsets) {
    if (threadIdx.x == 0) {
        int o = 0;
        for (int e = 0; e < NEXP; e++) { offsets[e] = o; o += counts[e]; }
    }
}

__global__ void assign_kernel(const int* __restrict__ topk_idx,
                              const float* __restrict__ topk_w,
                              const int* __restrict__ offsets,
                              int* __restrict__ cursor,
                              int* __restrict__ row_token,
                              float* __restrict__ row_w) {
    int t = blockIdx.x * blockDim.x + threadIdx.x;
    if (t >= T_TOKENS) return;
    for (int k = 0; k < 2; k++) {
        int e = topk_idx[t * 2 + k];
        int pos = atomicAdd(&cursor[e], 1);
        int slot = offsets[e] + pos;
        row_token[slot] = t;
        row_w[slot] = topk_w[t * 2 + k];
    }
}

__global__ void gather_kernel(const float* __restrict__ x,
                              const int* __restrict__ row_token,
                              ushort* __restrict__ xg) {
    int slot = blockIdx.x;
    int t = row_token[slot];
    const float4* src = (const float4*)(x + (size_t)t * DIM);
    ushort* dst = xg + (size_t)slot * DIM;
    int i = threadIdx.x;
    float4 v = src[i];
    ushort4 o; o.x = f2bf(v.x); o.y = f2bf(v.y); o.z = f2bf(v.z); o.w = f2bf(v.w);
    *(ushort4*)(dst + i * 4) = o;
}

// ---------------- GEMM 1: g/u + SwiGLU -> h (bf16) ----------------
// tile M=128 x N=64, BK=64; register-prefetch pipeline (k+1 loads in flight
// during tile-k MFMA); fp32 weights converted bf16 at ds_write.
// LDA=68 -> bank stride 34 words -> 2-per-bank starts (cheap).
#define LDA 68
__global__ __launch_bounds__(256) void gemm_gu_kernel(
    const ushort* __restrict__ xg,
    const float* __restrict__ w_gate,
    const float* __restrict__ w_up,
    const int* __restrict__ offsets, const int* __restrict__ counts,
    ushort* __restrict__ h) {
    int e = blockIdx.z;
    int cnt = counts[e];
    int rt = blockIdx.x * 128;
    if (rt >= cnt) return;
    int row0 = offsets[e] + rt;
    int rows_valid = cnt - rt; if (rows_valid > 128) rows_valid = 128;
    int col0 = blockIdx.y * 64;

    __shared__ ushort sA[128 * LDA];
    __shared__ ushort sG[64 * LDA];
    __shared__ ushort sU[64 * LDA];

    int tid = threadIdx.x;
    int wave = tid >> 6, lane = tid & 63;
    int wr = wave >> 1, wc = wave & 1;
    int lm = lane & 15, lq = lane >> 4;
    int rowA = tid >> 3;       // 0..31, +it*32
    int kg = tid & 7;          // 8-elem group within BK=64

    f32x4 accG[4][2] = {};
    f32x4 accU[4][2] = {};

    const ushort* aptr = xg + (size_t)row0 * DIM;
    const float* gbase = w_gate + (size_t)e * ISZ * DIM + (size_t)col0 * DIM;
    const float* ubase = w_up   + (size_t)e * ISZ * DIM + (size_t)col0 * DIM;

    uint4 pa[4];
    float4 pg[2][2], pu[2][2];

    auto prefetch = [&](int k0) {
#pragma unroll
        for (int it = 0; it < 4; it++)
            pa[it] = *(const uint4*)(aptr + (size_t)(it * 32 + rowA) * DIM + k0 + kg * 8);
#pragma unroll
        for (int it = 0; it < 2; it++) {
            const float* g = gbase + (size_t)(it * 32 + rowA) * DIM + k0 + kg * 8;
            pg[it][0] = *(const float4*)g;
            pg[it][1] = *(const float4*)(g + 4);
            const float* u = ubase + (size_t)(it * 32 + rowA) * DIM + k0 + kg * 8;
            pu[it][0] = *(const float4*)u;
            pu[it][1] = *(const float4*)(u + 4);
        }
    };

    prefetch(0);

    for (int k0 = 0; k0 < DIM; k0 += 64) {
        __syncthreads();
#pragma unroll
        for (int it = 0; it < 4; it++)
            *(uint4*)(sA + (it * 32 + rowA) * LDA + kg * 8) = pa[it];
#pragma unroll
        for (int it = 0; it < 2; it++) {
            cvt8_store(sG + (it * 32 + rowA) * LDA + kg * 8, pg[it][0], pg[it][1]);
            cvt8_store(sU + (it * 32 + rowA) * LDA + kg * 8, pu[it][0], pu[it][1]);
        }
        __syncthreads();
        if (k0 + 64 < DIM) prefetch(k0 + 64);   // fly during MFMA below

#pragma unroll
        for (int ks = 0; ks < 2; ks++) {
            bf16x8 a[4], bg[2], bu[2];
#pragma unroll
            for (int i = 0; i < 4; i++)
                a[i] = *(const bf16x8*)(sA + (wr * 64 + i * 16 + lm) * LDA + ks * 32 + lq * 8);
#pragma unroll
            for (int j = 0; j < 2; j++) {
                bg[j] = *(const bf16x8*)(sG + (wc * 32 + j * 16 + lm) * LDA + ks * 32 + lq * 8);
                bu[j] = *(const bf16x8*)(sU + (wc * 32 + j * 16 + lm) * LDA + ks * 32 + lq * 8);
            }
#pragma unroll
            for (int i = 0; i < 4; i++)
#pragma unroll
                for (int j = 0; j < 2; j++) {
                    accG[i][j] = __builtin_amdgcn_mfma_f32_16x16x32_bf16(a[i], bg[j], accG[i][j], 0, 0, 0);
                    accU[i][j] = __builtin_amdgcn_mfma_f32_16x16x32_bf16(a[i], bu[j], accU[i][j], 0, 0, 0);
                }
        }
    }

#pragma unroll
    for (int i = 0; i < 4; i++) {
        int rbase = wr * 64 + i * 16 + lq * 4;
#pragma unroll
        for (int r = 0; r < 4; r++) {
            int lrow = rbase + r;
            if (lrow < rows_valid) {
#pragma unroll
                for (int j = 0; j < 2; j++) {
                    float g = accG[i][j][r], u = accU[i][j][r];
                    float hv = g / (1.f + __expf(-g)) * u;
                    h[(size_t)(row0 + lrow) * ISZ + col0 + wc * 32 + j * 16 + lm] = f2bf(hv);
                }
            }
        }
    }
}

// ---------------- GEMM 2: h x w_down^T -> scaled atomic add into out ----------------
__global__ __launch_bounds__(256) void gemm_down_kernel(
    const ushort* __restrict__ h,
    const float* __restrict__ w_down,
    const int* __restrict__ offsets, const int* __restrict__ counts,
    const int* __restrict__ row_token, const float* __restrict__ row_w,
    float* __restrict__ out) {
    int e = blockIdx.z;
    int cnt = counts[e];
    int rt = blockIdx.x * 128;
    if (rt >= cnt) return;
    int row0 = offsets[e] + rt;
    int rows_valid = cnt - rt; if (rows_valid > 128) rows_valid = 128;
    int col0 = blockIdx.y * 64;

    __shared__ ushort sA[128 * LDA];
    __shared__ ushort sB[64 * LDA];

    int tid = threadIdx.x;
    int wave = tid >> 6, lane = tid & 63;
    int wr = wave >> 1, wc = wave & 1;
    int lm = lane & 15, lq = lane >> 4;
    int rowA = tid >> 3;
    int kg = tid & 7;

    f32x4 acc[4][2] = {};
    const ushort* aptr = h + (size_t)row0 * ISZ;
    const float* wbase = w_down + (size_t)e * DIM * ISZ + (size_t)col0 * ISZ;

    uint4 pa[4];
    float4 pb[2][2];

    auto prefetch = [&](int k0) {
#pragma unroll
        for (int it = 0; it < 4; it++)
            pa[it] = *(const uint4*)(aptr + (size_t)(it * 32 + rowA) * ISZ + k0 + kg * 8);
#pragma unroll
        for (int it = 0; it < 2; it++) {
            const float* wp = wbase + (size_t)(it * 32 + rowA) * ISZ + k0 + kg * 8;
            pb[it][0] = *(const float4*)wp;
            pb[it][1] = *(const float4*)(wp + 4);
        }
    };

    prefetch(0);

    for (int k0 = 0; k0 < ISZ; k0 += 64) {
        __syncthreads();
#pragma unroll
        for (int it = 0; it < 4; it++)
            *(uint4*)(sA + (it * 32 + rowA) * LDA + kg * 8) = pa[it];
#pragma unroll
        for (int it = 0; it < 2; it++)
            cvt8_store(sB + (it * 32 + rowA) * LDA + kg * 8, pb[it][0], pb[it][1]);
        __syncthreads();
        if (k0 + 64 < ISZ) prefetch(k0 + 64);

#pragma unroll
        for (int ks = 0; ks < 2; ks++) {
            bf16x8 a[4], b[2];
#pragma unroll
            for (int i = 0; i < 4; i++)
                a[i] = *(const bf16x8*)(sA + (wr * 64 + i * 16 + lm) * LDA + ks * 32 + lq * 8);
#pragma unroll
            for (int j = 0; j < 2; j++)
                b[j] = *(const bf16x8*)(sB + (wc * 32 + j * 16 + lm) * LDA + ks * 32 + lq * 8);
#pragma unroll
            for (int i = 0; i < 4; i++)
#pragma unroll
                for (int j = 0; j < 2; j++)
                    acc[i][j] = __builtin_amdgcn_mfma_f32_16x16x32_bf16(a[i], b[j], acc[i][j], 0, 0, 0);
        }
    }

#pragma unroll
    for (int i = 0; i < 4; i++) {
        int rbase = wr * 64 + i * 16 + lq * 4;
#pragma unroll
        for (int r = 0; r < 4; r++) {
            int lrow = rbase + r;
            if (lrow < rows_valid) {
                int slot = row0 + lrow;
                float sc = row_w[slot];
                int t = row_token[slot];
#pragma unroll
                for (int j = 0; j < 2; j++) {
                    int col = col0 + wc * 32 + j * 16 + lm;
                    atomicAdd(out + (size_t)t * DIM + col, acc[i][j][r] * sc);
                }
            }
        }
    }
}

extern "C" void kernel_launch(void* const* d_in, const int* in_sizes, int n_in,
                              void* d_out, int out_size, void* d_ws, size_t ws_size,
                              hipStream_t stream) {
    const float* x      = (const float*)d_in[0];
    const float* gate_w = (const float*)d_in[1];
    const float* w_gate = (const float*)d_in[2];
    const float* w_up   = (const float*)d_in[3];
    const float* w_down = (const float*)d_in[4];

    float* out = (float*)d_out;
    float* logits_out = out + (size_t)T_TOKENS * DIM;

    char* ws = (char*)d_ws;
    int*    counts    = (int*)(ws + OFF_COUNTS);
    int*    cursor    = (int*)(ws + OFF_CURSOR);
    int*    offsets   = (int*)(ws + OFF_OFFSETS);
    int*    topk_idx  = (int*)(ws + OFF_TOPK_I);
    float*  topk_w    = (float*)(ws + OFF_TOPK_W);
    int*    row_token = (int*)(ws + OFF_ROW_T);
    float*  row_w     = (float*)(ws + OFF_ROW_W);
    ushort* xg        = (ushort*)(ws + OFF_XG);
    ushort* h         = (ushort*)(ws + OFF_H);

    hipMemsetAsync(d_ws, 0, 128, stream);
    hipMemsetAsync(d_out, 0, (size_t)T_TOKENS * DIM * sizeof(float), stream);

    router_kernel<<<T_TOKENS / 4, 256, 0, stream>>>(x, gate_w, logits_out, topk_idx, topk_w, counts);
    scan_kernel<<<1, 64, 0, stream>>>(counts, offsets);
    assign_kernel<<<T_TOKENS / 256, 256, 0, stream>>>(topk_idx, topk_w, offsets, cursor, row_token, row_w);
    gather_kernel<<<NPAIRS, 256, 0, stream>>>(x, row_token, xg);

    dim3 g1(16, ISZ / 64, NEXP);   // 128-row tiles x 64-col tiles x experts
    gemm_gu_kernel<<<g1, 256, 0, stream>>>(xg, w_gate, w_up, offsets, counts, h);

    dim3 g2(16, DIM / 64, NEXP);
    gemm_down_kernel<<<g2, 256, 0, stream>>>(h, w_down, offsets, counts, row_token, row_w, out);
}

// Round 4
// 559.899 us; speedup vs baseline: 1.7118x; 1.7118x over previous
//
#include <hip/hip_runtime.h>

#define T_TOKENS 2048
#define DIM 1024
#define ISZ 2048
#define NEXP 8
#define NPAIRS (T_TOKENS * 2)
#define CAP (NPAIRS + 128)
#define MAXTILES 48

typedef __attribute__((ext_vector_type(8))) short bf16x8;
typedef __attribute__((ext_vector_type(4))) float f32x4;

constexpr size_t WELEMS = (size_t)NEXP * ISZ * DIM;   // 16.78M per weight tensor

// ---------------- ws layout ----------------
constexpr size_t OFF_COUNTS  = 0;     // 32 B
constexpr size_t OFF_CURSOR  = 32;    // 32 B
constexpr size_t OFF_OFFSETS = 64;    // 32 B
constexpr size_t OFF_NTILES  = 96;    // 4 B
constexpr size_t OFF_TILE_E  = 128;   // MAXTILES*4
constexpr size_t OFF_TILE_R0 = OFF_TILE_E  + MAXTILES * 4;
constexpr size_t OFF_TILE_NR = OFF_TILE_R0 + MAXTILES * 4;
constexpr size_t OFF_CTRL_END = OFF_TILE_NR + MAXTILES * 4;   // < 1024
constexpr size_t OFF_TOPK_I = 1024;
constexpr size_t OFF_TOPK_W = OFF_TOPK_I + (size_t)NPAIRS * 4;
constexpr size_t OFF_ROW_T  = OFF_TOPK_W + (size_t)NPAIRS * 4;
constexpr size_t OFF_ROW_W  = OFF_ROW_T + (size_t)CAP * 4;
constexpr size_t OFF_XG     = (OFF_ROW_W + (size_t)CAP * 4 + 255) & ~(size_t)255;
constexpr size_t OFF_H      = OFF_XG + (size_t)CAP * DIM * 2;
constexpr size_t OFF_WBF    = OFF_H + (size_t)CAP * ISZ * 2;
constexpr size_t WS_NEED_BF16 = OFF_WBF + 3 * WELEMS * 2;

__device__ __forceinline__ ushort f2bf(float f) {
    union { float f; unsigned u; } v; v.f = f;
    unsigned u = v.u;
    u += 0x7FFFu + ((u >> 16) & 1u);   // RNE
    return (ushort)(u >> 16);
}

__device__ __forceinline__ void cvt8_store(ushort* dst, float4 a, float4 b) {
    ushort4 c0; c0.x = f2bf(a.x); c0.y = f2bf(a.y); c0.z = f2bf(a.z); c0.w = f2bf(a.w);
    ushort4 c1; c1.x = f2bf(b.x); c1.y = f2bf(b.y); c1.z = f2bf(b.z); c1.w = f2bf(b.w);
    *(ushort4*)dst = c0;
    *(ushort4*)(dst + 4) = c1;
}

__device__ __forceinline__ bf16x8 cvt_frag(float4 a, float4 b) {
    bf16x8 r;
    r[0] = (short)f2bf(a.x); r[1] = (short)f2bf(a.y);
    r[2] = (short)f2bf(a.z); r[3] = (short)f2bf(a.w);
    r[4] = (short)f2bf(b.x); r[5] = (short)f2bf(b.y);
    r[6] = (short)f2bf(b.z); r[7] = (short)f2bf(b.w);
    return r;
}

// ---------------- weight fp32 -> bf16 (runs at ~6 TB/s) ----------------
__global__ __launch_bounds__(256) void cvt_w_kernel(const float* __restrict__ s0,
                                                    const float* __restrict__ s1,
                                                    const float* __restrict__ s2,
                                                    ushort* __restrict__ dst) {
    const float* src = (blockIdx.y == 0) ? s0 : (blockIdx.y == 1) ? s1 : s2;
    ushort* d = dst + (size_t)blockIdx.y * WELEMS;
    size_t i = (size_t)(blockIdx.x * blockDim.x + threadIdx.x) * 8;
    float4 a = *(const float4*)(src + i);
    float4 b = *(const float4*)(src + i + 4);
    cvt8_store(d + i, a, b);
}

// ---------------- router ----------------
__global__ void router_kernel(const float* __restrict__ x,
                              const float* __restrict__ gw,
                              float* __restrict__ logits_out,
                              int* __restrict__ topk_idx,
                              float* __restrict__ topk_w,
                              int* __restrict__ counts) {
    int gwave = (int)((blockIdx.x * blockDim.x + threadIdx.x) >> 6);
    int lane = threadIdx.x & 63;
    if (gwave >= T_TOKENS) return;
    const float* xr = x + (size_t)gwave * DIM;
    float xv[16];
#pragma unroll
    for (int i = 0; i < 16; i++) xv[i] = xr[i * 64 + lane];
    float lg[8];
#pragma unroll
    for (int e = 0; e < 8; e++) {
        const float* g = gw + e * DIM;
        float s = 0.f;
#pragma unroll
        for (int i = 0; i < 16; i++) s += xv[i] * g[i * 64 + lane];
#pragma unroll
        for (int off = 32; off > 0; off >>= 1) s += __shfl_xor(s, off, 64);
        lg[e] = s;
    }
    if (lane == 0) {
#pragma unroll
        for (int e = 0; e < 8; e++) logits_out[gwave * 8 + e] = lg[e];
        int e0 = 0; float l0 = lg[0];
#pragma unroll
        for (int e = 1; e < 8; e++) if (lg[e] > l0) { l0 = lg[e]; e0 = e; }
        int e1 = -1; float l1 = -1e30f;
#pragma unroll
        for (int e = 0; e < 8; e++) if (e != e0 && lg[e] > l1) { l1 = lg[e]; e1 = e; }
        float w0 = 1.f / (1.f + __expf(l1 - l0));
        float w1 = 1.f - w0;
        topk_idx[gwave * 2] = e0; topk_idx[gwave * 2 + 1] = e1;
        topk_w[gwave * 2] = w0;  topk_w[gwave * 2 + 1] = w1;
        atomicAdd(&counts[e0], 1);
        atomicAdd(&counts[e1], 1);
    }
}

// offsets + tile map (M=128 row tiles across experts)
__global__ void scan_kernel(const int* __restrict__ counts, int* __restrict__ offsets,
                            int* __restrict__ tile_e, int* __restrict__ tile_r0,
                            int* __restrict__ tile_nr, int* __restrict__ n_tiles) {
    if (threadIdx.x == 0) {
        int o = 0, nt = 0;
        for (int e = 0; e < NEXP; e++) {
            offsets[e] = o;
            int c = counts[e];
            for (int r = 0; r < c; r += 128) {
                tile_e[nt] = e; tile_r0[nt] = o + r;
                int nr = c - r; if (nr > 128) nr = 128;
                tile_nr[nt] = nr; nt++;
            }
            o += c;
        }
        *n_tiles = nt;
    }
}

__global__ void assign_kernel(const int* __restrict__ topk_idx,
                              const float* __restrict__ topk_w,
                              const int* __restrict__ offsets,
                              int* __restrict__ cursor,
                              int* __restrict__ row_token,
                              float* __restrict__ row_w) {
    int t = blockIdx.x * blockDim.x + threadIdx.x;
    if (t >= T_TOKENS) return;
    for (int k = 0; k < 2; k++) {
        int e = topk_idx[t * 2 + k];
        int pos = atomicAdd(&cursor[e], 1);
        int slot = offsets[e] + pos;
        row_token[slot] = t;
        row_w[slot] = topk_w[t * 2 + k];
    }
}

__global__ void gather_kernel(const float* __restrict__ x,
                              const int* __restrict__ row_token,
                              ushort* __restrict__ xg) {
    int slot = blockIdx.x;
    int t = row_token[slot];
    const float4* src = (const float4*)(x + (size_t)t * DIM);
    ushort* dst = xg + (size_t)slot * DIM;
    int i = threadIdx.x;
    float4 v = src[i];
    ushort4 o; o.x = f2bf(v.x); o.y = f2bf(v.y); o.z = f2bf(v.z); o.w = f2bf(v.w);
    *(ushort4*)(dst + i * 4) = o;
}

// ---------------- LDS-free, barrier-free GEMM 1 (gate+up+SwiGLU -> h) ----------------
// 1 wave per block. Wave tile: M=128 (8 x 16), N=32 (2 x 16), K-step 32.
// All fragments loaded global->register; register double-buffer keeps ~12 loads
// in flight continuously (no s_barrier, no vmcnt(0) drains).
template<typename WT>
__global__ __launch_bounds__(64, 2) void gemm_gu_kernel(
    const ushort* __restrict__ xg,
    const WT* __restrict__ w_gate,
    const WT* __restrict__ w_up,
    const int* __restrict__ tile_e, const int* __restrict__ tile_r0,
    const int* __restrict__ tile_nr,
    ushort* __restrict__ h) {
    int tile = blockIdx.x;
    int nr = tile_nr[tile];
    if (nr == 0) return;
    int e = tile_e[tile], row0 = tile_r0[tile];
    int col0 = blockIdx.y * 32;
    int lane = threadIdx.x;
    int lm = lane & 15, lq = lane >> 4;

    const ushort* ap = xg + (size_t)(row0 + lm) * DIM + lq * 8;
    const WT* gp = w_gate + (size_t)e * ISZ * DIM + (size_t)(col0 + lm) * DIM + lq * 8;
    const WT* up = w_up   + (size_t)e * ISZ * DIM + (size_t)(col0 + lm) * DIM + lq * 8;

    f32x4 accG[8][2] = {};
    f32x4 accU[8][2] = {};

    bf16x8 cA[8], cG[2], cU[2];
    bf16x8 nA[8], nG[2], nU[2];

    auto loadA = [&](int k, bf16x8* dst) {
#pragma unroll
        for (int i = 0; i < 8; i++)
            dst[i] = *(const bf16x8*)(ap + (size_t)i * 16 * DIM + k);
    };
    auto loadB = [&](int k, bf16x8* dg, bf16x8* du) {
#pragma unroll
        for (int j = 0; j < 2; j++) {
            if constexpr (sizeof(WT) == 2) {
                dg[j] = *(const bf16x8*)(gp + (size_t)j * 16 * DIM + k);
                du[j] = *(const bf16x8*)(up + (size_t)j * 16 * DIM + k);
            } else {
                const WT* g = gp + (size_t)j * 16 * DIM + k;
                const WT* u = up + (size_t)j * 16 * DIM + k;
                dg[j] = cvt_frag(*(const float4*)g, *(const float4*)(g + 4));
                du[j] = cvt_frag(*(const float4*)u, *(const float4*)(u + 4));
            }
        }
    };

    loadA(0, cA); loadB(0, cG, cU);
#pragma unroll 2
    for (int k = 0; k < DIM; k += 32) {
        if (k + 32 < DIM) { loadA(k + 32, nA); loadB(k + 32, nG, nU); }
#pragma unroll
        for (int i = 0; i < 8; i++)
#pragma unroll
            for (int j = 0; j < 2; j++) {
                accG[i][j] = __builtin_amdgcn_mfma_f32_16x16x32_bf16(cA[i], cG[j], accG[i][j], 0, 0, 0);
                accU[i][j] = __builtin_amdgcn_mfma_f32_16x16x32_bf16(cA[i], cU[j], accU[i][j], 0, 0, 0);
            }
#pragma unroll
        for (int i = 0; i < 8; i++) cA[i] = nA[i];
#pragma unroll
        for (int j = 0; j < 2; j++) { cG[j] = nG[j]; cU[j] = nU[j]; }
    }

#pragma unroll
    for (int i = 0; i < 8; i++) {
#pragma unroll
        for (int r = 0; r < 4; r++) {
            int lrow = i * 16 + lq * 4 + r;
            if (lrow < nr) {
#pragma unroll
                for (int j = 0; j < 2; j++) {
                    float g = accG[i][j][r], u = accU[i][j][r];
                    float hv = g / (1.f + __expf(-g)) * u;
                    h[(size_t)(row0 + lrow) * ISZ + col0 + j * 16 + lm] = f2bf(hv);
                }
            }
        }
    }
}

// ---------------- LDS-free GEMM 2 (h x w_down^T -> scaled atomic out) ----------------
template<typename WT>
__global__ __launch_bounds__(64, 2) void gemm_down_kernel(
    const ushort* __restrict__ h,
    const WT* __restrict__ w_down,
    const int* __restrict__ tile_e, const int* __restrict__ tile_r0,
    const int* __restrict__ tile_nr,
    const int* __restrict__ row_token, const float* __restrict__ row_w,
    float* __restrict__ out) {
    int tile = blockIdx.x;
    int nr = tile_nr[tile];
    if (nr == 0) return;
    int e = tile_e[tile], row0 = tile_r0[tile];
    int col0 = blockIdx.y * 32;
    int lane = threadIdx.x;
    int lm = lane & 15, lq = lane >> 4;

    const ushort* ap = h + (size_t)(row0 + lm) * ISZ + lq * 8;
    const WT* bp = w_down + (size_t)e * DIM * ISZ + (size_t)(col0 + lm) * ISZ + lq * 8;

    f32x4 acc[8][2] = {};
    bf16x8 cA[8], cB[2], nA[8], nB[2];

    auto loadA = [&](int k, bf16x8* dst) {
#pragma unroll
        for (int i = 0; i < 8; i++)
            dst[i] = *(const bf16x8*)(ap + (size_t)i * 16 * ISZ + k);
    };
    auto loadB = [&](int k, bf16x8* db) {
#pragma unroll
        for (int j = 0; j < 2; j++) {
            if constexpr (sizeof(WT) == 2) {
                db[j] = *(const bf16x8*)(bp + (size_t)j * 16 * ISZ + k);
            } else {
                const WT* b = bp + (size_t)j * 16 * ISZ + k;
                db[j] = cvt_frag(*(const float4*)b, *(const float4*)(b + 4));
            }
        }
    };

    loadA(0, cA); loadB(0, cB);
#pragma unroll 2
    for (int k = 0; k < ISZ; k += 32) {
        if (k + 32 < ISZ) { loadA(k + 32, nA); loadB(k + 32, nB); }
#pragma unroll
        for (int i = 0; i < 8; i++)
#pragma unroll
            for (int j = 0; j < 2; j++)
                acc[i][j] = __builtin_amdgcn_mfma_f32_16x16x32_bf16(cA[i], cB[j], acc[i][j], 0, 0, 0);
#pragma unroll
        for (int i = 0; i < 8; i++) cA[i] = nA[i];
#pragma unroll
        for (int j = 0; j < 2; j++) cB[j] = nB[j];
    }

#pragma unroll
    for (int i = 0; i < 8; i++) {
#pragma unroll
        for (int r = 0; r < 4; r++) {
            int lrow = i * 16 + lq * 4 + r;
            if (lrow < nr) {
                int slot = row0 + lrow;
                float sc = row_w[slot];
                int t = row_token[slot];
#pragma unroll
                for (int j = 0; j < 2; j++) {
                    int col = col0 + j * 16 + lm;
                    atomicAdd(out + (size_t)t * DIM + col, acc[i][j][r] * sc);
                }
            }
        }
    }
}

extern "C" void kernel_launch(void* const* d_in, const int* in_sizes, int n_in,
                              void* d_out, int out_size, void* d_ws, size_t ws_size,
                              hipStream_t stream) {
    const float* x      = (const float*)d_in[0];
    const float* gate_w = (const float*)d_in[1];
    const float* w_gate = (const float*)d_in[2];
    const float* w_up   = (const float*)d_in[3];
    const float* w_down = (const float*)d_in[4];

    float* out = (float*)d_out;
    float* logits_out = out + (size_t)T_TOKENS * DIM;

    char* ws = (char*)d_ws;
    int*    counts    = (int*)(ws + OFF_COUNTS);
    int*    cursor    = (int*)(ws + OFF_CURSOR);
    int*    offsets   = (int*)(ws + OFF_OFFSETS);
    int*    n_tiles   = (int*)(ws + OFF_NTILES);
    int*    tile_e    = (int*)(ws + OFF_TILE_E);
    int*    tile_r0   = (int*)(ws + OFF_TILE_R0);
    int*    tile_nr   = (int*)(ws + OFF_TILE_NR);
    int*    topk_idx  = (int*)(ws + OFF_TOPK_I);
    float*  topk_w    = (float*)(ws + OFF_TOPK_W);
    int*    row_token = (int*)(ws + OFF_ROW_T);
    float*  row_w     = (float*)(ws + OFF_ROW_W);
    ushort* xg        = (ushort*)(ws + OFF_XG);
    ushort* h         = (ushort*)(ws + OFF_H);
    ushort* wbf       = (ushort*)(ws + OFF_WBF);

    hipMemsetAsync(d_ws, 0, 1024, stream);   // counts/cursor/offsets + tile map (dead tiles -> nr=0)
    hipMemsetAsync(d_out, 0, (size_t)T_TOKENS * DIM * sizeof(float), stream);

    router_kernel<<<T_TOKENS / 4, 256, 0, stream>>>(x, gate_w, logits_out, topk_idx, topk_w, counts);
    scan_kernel<<<1, 64, 0, stream>>>(counts, offsets, tile_e, tile_r0, tile_nr, n_tiles);
    assign_kernel<<<T_TOKENS / 256, 256, 0, stream>>>(topk_idx, topk_w, offsets, cursor, row_token, row_w);
    gather_kernel<<<NPAIRS, 256, 0, stream>>>(x, row_token, xg);

    bool use_bf16 = (ws_size >= WS_NEED_BF16);
    if (use_bf16) {
        dim3 gc((unsigned)(WELEMS / 8 / 256), 3);
        cvt_w_kernel<<<gc, 256, 0, stream>>>(w_gate, w_up, w_down, wbf);
        const ushort* wg_bf = wbf;
        const ushort* wu_bf = wbf + WELEMS;
        const ushort* wd_bf = wbf + 2 * WELEMS;

        dim3 g1(MAXTILES, ISZ / 32);
        gemm_gu_kernel<ushort><<<g1, 64, 0, stream>>>(xg, wg_bf, wu_bf, tile_e, tile_r0, tile_nr, h);
        dim3 g2(MAXTILES, DIM / 32);
        gemm_down_kernel<ushort><<<g2, 64, 0, stream>>>(h, wd_bf, tile_e, tile_r0, tile_nr, row_token, row_w, out);
    } else {
        dim3 g1(MAXTILES, ISZ / 32);
        gemm_gu_kernel<float><<<g1, 64, 0, stream>>>(xg, w_gate, w_up, tile_e, tile_r0, tile_nr, h);
        dim3 g2(MAXTILES, DIM / 32);
        gemm_down_kernel<float><<<g2, 64, 0, stream>>>(h, w_down, tile_e, tile_r0, tile_nr, row_token, row_w, out);
    }
}